// Round 3
// baseline (393.801 us; speedup 1.0000x reference)
//
#include <hip/hip_runtime.h>
#include <math.h>

// Problem constants
#define B_SZ   512
#define L_SEQ  30
#define F_DIM  64
#define N_LEAD 500
#define MAXLAG 10
#define H_DIM  64
#define NROWS  5000          // N_LEAD * MAXLAG
#define TOPK   5

// Output layout (flat float32):
// pred [512] | top_k_indices [512*5*2] | top_k_scores [512*5] | attn [512*5000]
#define OFF_IDX   512
#define OFF_SCORE 5632
#define OFF_ATTN  8192

__device__ __forceinline__ float fast_sigmoid(float x) {
    return 1.f / (1.f + __expf(-x));
}
__device__ __forceinline__ float fast_tanh(float x) {
    float ax = fabsf(x);
    float t  = __expf(-2.f * ax);
    float r  = (1.f - t) / (1.f + t);
    return copysignf(r, x);
}
__device__ __forceinline__ float sfl(float v) {   // force to SGPR
    return __uint_as_float(__builtin_amdgcn_readfirstlane(__float_as_uint(v)));
}

// 16 x float4 dot with 4 partial accumulators (16-deep chains instead of 64)
__device__ __forceinline__ float dot16(const float4* __restrict__ w,
                                       const float4* __restrict__ v) {
    float a0 = 0.f, a1 = 0.f, a2 = 0.f, a3 = 0.f;
#pragma unroll
    for (int k = 0; k < 16; k += 4) {
        a0 += w[k+0].x*v[k+0].x + w[k+0].y*v[k+0].y + w[k+0].z*v[k+0].z + w[k+0].w*v[k+0].w;
        a1 += w[k+1].x*v[k+1].x + w[k+1].y*v[k+1].y + w[k+1].z*v[k+1].z + w[k+1].w*v[k+1].w;
        a2 += w[k+2].x*v[k+2].x + w[k+2].y*v[k+2].y + w[k+2].z*v[k+2].z + w[k+2].w*v[k+2].w;
        a3 += w[k+3].x*v[k+3].x + w[k+3].y*v[k+3].y + w[k+3].z*v[k+3].z + w[k+3].w*v[k+3].w;
    }
    return (a0 + a1) + (a2 + a3);
}

// ---------------------------------------------------------------------------
// Kernel A: LSTM (30 steps) + query = h@W_Q^T + kq = query@W_K  -> kq[B,64]
// One block per batch element; 256 threads = one per gate row.
// ---------------------------------------------------------------------------
__global__ __launch_bounds__(256) void lstm_kq_kernel(
    const float* __restrict__ x,      // [B,30,64]
    const float* __restrict__ W_ih,   // [256,64]
    const float* __restrict__ W_hh,   // [256,64]
    const float* __restrict__ b_ih,   // [256]
    const float* __restrict__ b_hh,   // [256]
    const float* __restrict__ W_Q,    // [64,64]
    const float* __restrict__ W_K,    // [64,64]
    float* __restrict__ kq)           // [B,64]
{
    __shared__ __align__(16) float xs[L_SEQ * F_DIM];   // 7.5 KB
    __shared__ __align__(16) float hs[H_DIM];
    __shared__ __align__(16) float gates[256];

    const int b = blockIdx.x;
    const int t = threadIdx.x;

    for (int i = t; i < L_SEQ * F_DIM; i += 256)
        xs[i] = x[b * L_SEQ * F_DIM + i];
    if (t < H_DIM) hs[t] = 0.f;

    // per-thread weight rows in registers (64+64 floats)
    float4 wih[16], whh[16];
    const float4* wihp = (const float4*)(W_ih + t * 64);
    const float4* whhp = (const float4*)(W_hh + t * 64);
#pragma unroll
    for (int k = 0; k < 16; ++k) { wih[k] = wihp[k]; whh[k] = whhp[k]; }
    const float bsum = b_ih[t] + b_hh[t];

    float c = 0.f;
    __syncthreads();

    // x-projection for step 0 (xs now valid)
    float gx = bsum + dot16(wih, (const float4*)xs);

    for (int step = 0; step < L_SEQ; ++step) {
        float g = gx + dot16(whh, (const float4*)hs);
        gates[t] = g;
        __syncthreads();
        if (t < H_DIM) {
            float ig = fast_sigmoid(gates[t]);
            float fg = fast_sigmoid(gates[t + 64]);
            float gg = fast_tanh(gates[t + 128]);
            float og = fast_sigmoid(gates[t + 192]);
            c = fg * c + ig * gg;
            hs[t] = og * fast_tanh(c);
        }
        // next step's x-projection overlaps the h-update / barrier shadow
        if (step + 1 < L_SEQ)
            gx = bsum + dot16(wih, (const float4*)(xs + (step + 1) * F_DIM));
        __syncthreads();
    }

    // query[j] = dot(W_Q[j,:], h_last)   (reuse gates[] as query storage)
    if (t < H_DIM)
        gates[t] = dot16((const float4*)(W_Q + t * 64), (const float4*)hs);
    __syncthreads();
    // kq[f] = sum_h query[h] * W_K[h,f]  (coalesced over f)
    if (t < F_DIM) {
        float a0 = 0.f, a1 = 0.f;
        for (int h = 0; h < H_DIM; h += 2) {
            a0 += gates[h]     * W_K[h * F_DIM + t];
            a1 += gates[h + 1] * W_K[(h + 1) * F_DIM + t];
        }
        kq[b * F_DIM + t] = a0 + a1;
    }
}

// ---------------------------------------------------------------------------
// Kernel B (fused): attn GEMV + write attn + top-5 + softmax + gather + MLP
// One block per batch element. 512 threads. Row-per-lane streaming, kq in SGPRs.
// NOTE: no min-waves clause — round-2's (512,8) may have forced VGPR<=64 and
// spilled the 8-float4-in-flight streaming body.
// ---------------------------------------------------------------------------
__global__ __launch_bounds__(512) void fused_attn_topk_kernel(
    const float* __restrict__ raw,    // [B*5000*64]
    const float* __restrict__ kq,     // [B,64]
    const float* __restrict__ Wp1, const float* __restrict__ bp1,
    const float* __restrict__ Wp2, const float* __restrict__ bp2,
    const float* __restrict__ Wp3, const float* __restrict__ bp3,
    float* __restrict__ out)
{
    __shared__ float av[NROWS];       // 20 KB
    __shared__ float redv[8];
    __shared__ int   redi[8];
    __shared__ float topv[TOPK];
    __shared__ int   topi[TOPK];
    __shared__ float sc[TOPK];
    __shared__ __align__(16) float wsum[64];
    __shared__ __align__(16) float h1[64];
    __shared__ float h2[32];

    const int b = blockIdx.x, t = threadIdx.x;

    // ---- kq into SGPRs (block-uniform) ----
    const float* kqp = kq + b * 64;
#define LQ(i) const float q##i##x = sfl(kqp[4*(i)+0]), q##i##y = sfl(kqp[4*(i)+1]), \
                          q##i##z = sfl(kqp[4*(i)+2]), q##i##w = sfl(kqp[4*(i)+3]);
    LQ(0) LQ(1) LQ(2) LQ(3) LQ(4) LQ(5) LQ(6) LQ(7)
    LQ(8) LQ(9) LQ(10) LQ(11) LQ(12) LQ(13) LQ(14) LQ(15)
#undef LQ

    // ---- Phase 1: attn[b, r] = dot(raw[b,r,:], kq)/8 ; row r = pass*512 + t
    float* attn_g = out + OFF_ATTN + (size_t)b * NROWS;
    const float4* p = (const float4*)raw + ((size_t)b * NROWS + t) * 16;

#define DOT4(acc, v, i) acc += v.x*q##i##x + v.y*q##i##y + v.z*q##i##z + v.w*q##i##w;
#define BODY(r) { \
    float4 v0=p[0],v1=p[1],v2=p[2],v3=p[3],v4=p[4],v5=p[5],v6=p[6],v7=p[7]; \
    float s0=0.f,s1=0.f,s2=0.f,s3=0.f; \
    DOT4(s0,v0,0) DOT4(s1,v1,1) DOT4(s2,v2,2) DOT4(s3,v3,3) \
    DOT4(s0,v4,4) DOT4(s1,v5,5) DOT4(s2,v6,6) DOT4(s3,v7,7) \
    v0=p[8];v1=p[9];v2=p[10];v3=p[11];v4=p[12];v5=p[13];v6=p[14];v7=p[15]; \
    DOT4(s0,v0,8)  DOT4(s1,v1,9)  DOT4(s2,v2,10) DOT4(s3,v3,11) \
    DOT4(s0,v4,12) DOT4(s1,v5,13) DOT4(s2,v6,14) DOT4(s3,v7,15) \
    float s = ((s0+s1)+(s2+s3)) * 0.125f; \
    av[r] = s; attn_g[r] = s; }

    int r = t;
#pragma unroll 1
    for (int pass = 0; pass < 9; ++pass) {      // 9 full passes: rows 0..4607
        BODY(r)
        r += 512; p += 512 * 16;
    }
    if (r < NROWS) { BODY(r) }                  // tail: rows 4608..4999
#undef BODY
#undef DOT4
    __syncthreads();

    // ---- Phase 2: 5 sequential argmax passes (lax.top_k tie semantics) ----
    for (int pp = 0; pp < TOPK; ++pp) {
        float bv = -INFINITY; int bi = 0x7fffffff;
        for (int i = t; i < NROWS; i += 512) {
            float v = av[i];
            if (v > bv || (v == bv && i < bi)) { bv = v; bi = i; }
        }
#pragma unroll
        for (int m = 32; m >= 1; m >>= 1) {
            float ov = __shfl_xor(bv, m);
            int   oi = __shfl_xor(bi, m);
            if (ov > bv || (ov == bv && oi < bi)) { bv = ov; bi = oi; }
        }
        if ((t & 63) == 0) { redv[t >> 6] = bv; redi[t >> 6] = bi; }
        __syncthreads();
        if (t == 0) {
            for (int w = 1; w < 8; ++w)
                if (redv[w] > bv || (redv[w] == bv && redi[w] < bi)) { bv = redv[w]; bi = redi[w]; }
            topv[pp] = bv; topi[pp] = bi;
            av[bi] = -INFINITY;
        }
        __syncthreads();
    }

    // ---- Phase 3: softmax + index outputs + gather + MLP ----
    if (t == 0) {
        float mx = topv[0];   // pass 0 found the global max
        float e[TOPK], s = 0.f;
#pragma unroll
        for (int k = 0; k < TOPK; ++k) { e[k] = __expf(topv[k] - mx); s += e[k]; }
        float inv = 1.f / s;
#pragma unroll
        for (int k = 0; k < TOPK; ++k) {
            sc[k] = e[k] * inv;
            out[OFF_IDX + b * 10 + 2 * k]     = (float)(topi[k] / MAXLAG);
            out[OFF_IDX + b * 10 + 2 * k + 1] = (float)(topi[k] % MAXLAG);
            out[OFF_SCORE + b * TOPK + k]     = sc[k];
        }
    }
    __syncthreads();

    if (t < 64) {
        float acc = 0.f;
#pragma unroll
        for (int k = 0; k < TOPK; ++k)
            acc += sc[k] * raw[((size_t)b * NROWS + topi[k]) * 64 + t];
        wsum[t] = acc;
    }
    __syncthreads();
    if (t < 64) {
        float a = bp1[t];
        const float4* w = (const float4*)(Wp1 + t * 64);
        const float4* v = (const float4*)wsum;
#pragma unroll
        for (int k = 0; k < 16; ++k)
            a += w[k].x*v[k].x + w[k].y*v[k].y + w[k].z*v[k].z + w[k].w*v[k].w;
        h1[t] = fmaxf(a, 0.f);
    }
    __syncthreads();
    if (t < 32) {
        float a = bp2[t];
        const float4* w = (const float4*)(Wp2 + t * 64);
        const float4* v = (const float4*)h1;
#pragma unroll
        for (int k = 0; k < 16; ++k)
            a += w[k].x*v[k].x + w[k].y*v[k].y + w[k].z*v[k].z + w[k].w*v[k].w;
        h2[t] = fmaxf(a, 0.f);
    }
    __syncthreads();
    if (t == 0) {
        float a = bp3[0];
#pragma unroll
        for (int f = 0; f < 32; ++f) a += Wp3[f] * h2[f];
        out[b] = a;
    }
}

// ---------------------------------------------------------------------------
// ATTRIBUTION ROUND: fused kernel launched TWICE (idempotent — recomputes all
// values from raw/kq and rewrites identical outputs). T_fused = total - 207us.
// ---------------------------------------------------------------------------
extern "C" void kernel_launch(void* const* d_in, const int* in_sizes, int n_in,
                              void* d_out, int out_size, void* d_ws, size_t ws_size,
                              hipStream_t stream) {
    const float* target = (const float*)d_in[0];
    const float* raw    = (const float*)d_in[1];
    const float* W_ih   = (const float*)d_in[2];
    const float* W_hh   = (const float*)d_in[3];
    const float* b_ih   = (const float*)d_in[4];
    const float* b_hh   = (const float*)d_in[5];
    const float* W_Q    = (const float*)d_in[6];
    const float* W_K    = (const float*)d_in[7];
    const float* Wp1    = (const float*)d_in[8];
    const float* bp1    = (const float*)d_in[9];
    const float* Wp2    = (const float*)d_in[10];
    const float* bp2    = (const float*)d_in[11];
    const float* Wp3    = (const float*)d_in[12];
    const float* bp3    = (const float*)d_in[13];

    float* out = (float*)d_out;
    float* kq  = (float*)d_ws;                 // [512*64] floats

    hipLaunchKernelGGL(lstm_kq_kernel, dim3(B_SZ), dim3(256), 0, stream,
                       target, W_ih, W_hh, b_ih, b_hh, W_Q, W_K, kq);
    hipLaunchKernelGGL(fused_attn_topk_kernel, dim3(B_SZ), dim3(512), 0, stream,
                       raw, kq, Wp1, bp1, Wp2, bp2, Wp3, bp3, out);
    hipLaunchKernelGGL(fused_attn_topk_kernel, dim3(B_SZ), dim3(512), 0, stream,
                       raw, kq, Wp1, bp1, Wp2, bp2, Wp3, bp3, out);
}

// Round 4
// 242.646 us; speedup vs baseline: 1.6229x; 1.6229x over previous
//
#include <hip/hip_runtime.h>
#include <math.h>

// Problem constants
#define B_SZ   512
#define L_SEQ  30
#define F_DIM  64
#define N_LEAD 500
#define MAXLAG 10
#define H_DIM  64
#define NROWS  5000          // N_LEAD * MAXLAG
#define TOPK   5

// Output layout (flat float32):
// pred [512] | top_k_indices [512*5*2] | top_k_scores [512*5] | attn [512*5000]
#define OFF_IDX   512
#define OFF_SCORE 5632
#define OFF_ATTN  8192

__device__ __forceinline__ float fast_sigmoid(float x) {
    return 1.f / (1.f + __expf(-x));
}
__device__ __forceinline__ float fast_tanh(float x) {
    float ax = fabsf(x);
    float t  = __expf(-2.f * ax);
    float r  = (1.f - t) / (1.f + t);
    return copysignf(r, x);
}
__device__ __forceinline__ float sfl(float v) {   // force to SGPR
    return __uint_as_float(__builtin_amdgcn_readfirstlane(__float_as_uint(v)));
}

// 16 x float4 dot with 4 partial accumulators
__device__ __forceinline__ float dot16(const float4* __restrict__ w,
                                       const float4* __restrict__ v) {
    float a0 = 0.f, a1 = 0.f, a2 = 0.f, a3 = 0.f;
#pragma unroll
    for (int k = 0; k < 16; k += 4) {
        a0 += w[k+0].x*v[k+0].x + w[k+0].y*v[k+0].y + w[k+0].z*v[k+0].z + w[k+0].w*v[k+0].w;
        a1 += w[k+1].x*v[k+1].x + w[k+1].y*v[k+1].y + w[k+1].z*v[k+1].z + w[k+1].w*v[k+1].w;
        a2 += w[k+2].x*v[k+2].x + w[k+2].y*v[k+2].y + w[k+2].z*v[k+2].z + w[k+2].w*v[k+2].w;
        a3 += w[k+3].x*v[k+3].x + w[k+3].y*v[k+3].y + w[k+3].z*v[k+3].z + w[k+3].w*v[k+3].w;
    }
    return (a0 + a1) + (a2 + a3);
}

// ---------------------------------------------------------------------------
// Kernel A: LSTM (30 steps) + query = h@W_Q^T + kq = query@W_K  -> kq[B,64]
// (unchanged — measured at ~<20us including all overheads)
// ---------------------------------------------------------------------------
__global__ __launch_bounds__(256) void lstm_kq_kernel(
    const float* __restrict__ x,      // [B,30,64]
    const float* __restrict__ W_ih,   // [256,64]
    const float* __restrict__ W_hh,   // [256,64]
    const float* __restrict__ b_ih,   // [256]
    const float* __restrict__ b_hh,   // [256]
    const float* __restrict__ W_Q,    // [64,64]
    const float* __restrict__ W_K,    // [64,64]
    float* __restrict__ kq)           // [B,64]
{
    __shared__ __align__(16) float xs[L_SEQ * F_DIM];   // 7.5 KB
    __shared__ __align__(16) float hs[H_DIM];
    __shared__ __align__(16) float gates[256];

    const int b = blockIdx.x;
    const int t = threadIdx.x;

    for (int i = t; i < L_SEQ * F_DIM; i += 256)
        xs[i] = x[b * L_SEQ * F_DIM + i];
    if (t < H_DIM) hs[t] = 0.f;

    float4 wih[16], whh[16];
    const float4* wihp = (const float4*)(W_ih + t * 64);
    const float4* whhp = (const float4*)(W_hh + t * 64);
#pragma unroll
    for (int k = 0; k < 16; ++k) { wih[k] = wihp[k]; whh[k] = whhp[k]; }
    const float bsum = b_ih[t] + b_hh[t];

    float c = 0.f;
    __syncthreads();

    float gx = bsum + dot16(wih, (const float4*)xs);

    for (int step = 0; step < L_SEQ; ++step) {
        float g = gx + dot16(whh, (const float4*)hs);
        gates[t] = g;
        __syncthreads();
        if (t < H_DIM) {
            float ig = fast_sigmoid(gates[t]);
            float fg = fast_sigmoid(gates[t + 64]);
            float gg = fast_tanh(gates[t + 128]);
            float og = fast_sigmoid(gates[t + 192]);
            c = fg * c + ig * gg;
            hs[t] = og * fast_tanh(c);
        }
        if (step + 1 < L_SEQ)
            gx = bsum + dot16(wih, (const float4*)(xs + (step + 1) * F_DIM));
        __syncthreads();
    }

    if (t < H_DIM)
        gates[t] = dot16((const float4*)(W_Q + t * 64), (const float4*)hs);
    __syncthreads();
    if (t < F_DIM) {
        float a0 = 0.f, a1 = 0.f;
        for (int h = 0; h < H_DIM; h += 2) {
            a0 += gates[h]     * W_K[h * F_DIM + t];
            a1 += gates[h + 1] * W_K[(h + 1) * F_DIM + t];
        }
        kq[b * F_DIM + t] = a0 + a1;
    }
}

// ---------------------------------------------------------------------------
// Kernel B: attn streaming GEMV. H1 test: 32 waves/CU.
// 2048 blocks x 256 threads, <=64 VGPR (launch_bounds(256,8)), zero LDS,
// 4-deep load pipeline, kq in SGPRs, one row per lane.
// ---------------------------------------------------------------------------
#define RPB 1250   // rows per block (4 blocks per batch)
__global__ __launch_bounds__(256, 8) void attn_stream_kernel(
    const float4* __restrict__ raw,   // [B*5000*16] float4
    const float* __restrict__ kq,     // [B,64]
    float* __restrict__ attn)         // [B*5000]
{
    const int b = blockIdx.x >> 2;
    const int q = blockIdx.x & 3;
    const int t = threadIdx.x;

    const float* kqp = kq + b * 64;
#define LQ(i) const float q##i##x = sfl(kqp[4*(i)+0]), q##i##y = sfl(kqp[4*(i)+1]), \
                          q##i##z = sfl(kqp[4*(i)+2]), q##i##w = sfl(kqp[4*(i)+3]);
    LQ(0) LQ(1) LQ(2) LQ(3) LQ(4) LQ(5) LQ(6) LQ(7)
    LQ(8) LQ(9) LQ(10) LQ(11) LQ(12) LQ(13) LQ(14) LQ(15)
#undef LQ

    const int row0 = q * RPB;
    const float4* p = raw + ((size_t)b * NROWS + row0 + t) * 16;
    float*       ag = attn + (size_t)b * NROWS + row0 + t;

#define DOT4(acc, v, i) acc += v.x*q##i##x + v.y*q##i##y + v.z*q##i##z + v.w*q##i##w;
#define BODY() { \
    float4 v0=p[0],v1=p[1],v2=p[2],v3=p[3]; \
    float s0=0.f,s1=0.f,s2=0.f,s3=0.f; \
    DOT4(s0,v0,0) DOT4(s1,v1,1) DOT4(s2,v2,2) DOT4(s3,v3,3) \
    v0=p[4];v1=p[5];v2=p[6];v3=p[7]; \
    DOT4(s0,v0,4) DOT4(s1,v1,5) DOT4(s2,v2,6) DOT4(s3,v3,7) \
    v0=p[8];v1=p[9];v2=p[10];v3=p[11]; \
    DOT4(s0,v0,8) DOT4(s1,v1,9) DOT4(s2,v2,10) DOT4(s3,v3,11) \
    v0=p[12];v1=p[13];v2=p[14];v3=p[15]; \
    DOT4(s0,v0,12) DOT4(s1,v1,13) DOT4(s2,v2,14) DOT4(s3,v3,15) \
    *ag = ((s0+s1)+(s2+s3)) * 0.125f; }

#pragma unroll 1
    for (int i = 0; i < 4; ++i) {        // rows row0 .. row0+1023
        BODY()
        p += 256 * 16; ag += 256;
    }
    if (t < RPB - 1024) {                // tail: 226 rows
        BODY()
    }
#undef BODY
#undef DOT4
}

// ---------------------------------------------------------------------------
// Kernel C: per-batch top-5 (lax.top_k tie semantics) + softmax + gather + MLP
// Reads attn back from global (L2/L3-resident, ~10MB). 256 threads/block.
// ---------------------------------------------------------------------------
__global__ __launch_bounds__(256) void topk_mlp_kernel(
    const float* __restrict__ attn,   // [B*5000]
    const float* __restrict__ raw,    // [B*5000*64]
    const float* __restrict__ Wp1, const float* __restrict__ bp1,
    const float* __restrict__ Wp2, const float* __restrict__ bp2,
    const float* __restrict__ Wp3, const float* __restrict__ bp3,
    float* __restrict__ out)
{
    __shared__ __align__(16) float av[NROWS];       // 20 KB
    __shared__ float redv[4];
    __shared__ int   redi[4];
    __shared__ float topv[TOPK];
    __shared__ int   topi[TOPK];
    __shared__ float sc[TOPK];
    __shared__ __align__(16) float wsum[64];
    __shared__ __align__(16) float h1[64];
    __shared__ float h2[32];

    const int b = blockIdx.x, t = threadIdx.x;

    // coalesced float4 copy of the attn row into LDS
    const float4* ain = (const float4*)(attn + (size_t)b * NROWS);
    float4* av4 = (float4*)av;
    for (int i = t; i < NROWS / 4; i += 256) av4[i] = ain[i];
    __syncthreads();

    // 5 sequential argmax passes; ties -> lowest index
    for (int pp = 0; pp < TOPK; ++pp) {
        float bv = -INFINITY; int bi = 0x7fffffff;
        for (int i = t; i < NROWS; i += 256) {
            float v = av[i];
            if (v > bv || (v == bv && i < bi)) { bv = v; bi = i; }
        }
#pragma unroll
        for (int m = 32; m >= 1; m >>= 1) {
            float ov = __shfl_xor(bv, m);
            int   oi = __shfl_xor(bi, m);
            if (ov > bv || (ov == bv && oi < bi)) { bv = ov; bi = oi; }
        }
        if ((t & 63) == 0) { redv[t >> 6] = bv; redi[t >> 6] = bi; }
        __syncthreads();
        if (t == 0) {
            for (int w = 1; w < 4; ++w)
                if (redv[w] > bv || (redv[w] == bv && redi[w] < bi)) { bv = redv[w]; bi = redi[w]; }
            topv[pp] = bv; topi[pp] = bi;
            av[bi] = -INFINITY;
        }
        __syncthreads();
    }

    if (t == 0) {
        float mx = topv[0];
        float e[TOPK], s = 0.f;
#pragma unroll
        for (int k = 0; k < TOPK; ++k) { e[k] = __expf(topv[k] - mx); s += e[k]; }
        float inv = 1.f / s;
#pragma unroll
        for (int k = 0; k < TOPK; ++k) {
            sc[k] = e[k] * inv;
            out[OFF_IDX + b * 10 + 2 * k]     = (float)(topi[k] / MAXLAG);
            out[OFF_IDX + b * 10 + 2 * k + 1] = (float)(topi[k] % MAXLAG);
            out[OFF_SCORE + b * TOPK + k]     = sc[k];
        }
    }
    __syncthreads();

    if (t < 64) {
        float acc = 0.f;
#pragma unroll
        for (int k = 0; k < TOPK; ++k)
            acc += sc[k] * raw[((size_t)b * NROWS + topi[k]) * 64 + t];
        wsum[t] = acc;
    }
    __syncthreads();
    if (t < 64) {
        float a = bp1[t];
        const float4* w = (const float4*)(Wp1 + t * 64);
        const float4* v = (const float4*)wsum;
#pragma unroll
        for (int k = 0; k < 16; ++k)
            a += w[k].x*v[k].x + w[k].y*v[k].y + w[k].z*v[k].z + w[k].w*v[k].w;
        h1[t] = fmaxf(a, 0.f);
    }
    __syncthreads();
    if (t < 32) {
        float a = bp2[t];
        const float4* w = (const float4*)(Wp2 + t * 64);
        const float4* v = (const float4*)h1;
#pragma unroll
        for (int k = 0; k < 16; ++k)
            a += w[k].x*v[k].x + w[k].y*v[k].y + w[k].z*v[k].z + w[k].w*v[k].w;
        h2[t] = fmaxf(a, 0.f);
    }
    __syncthreads();
    if (t == 0) {
        float a = bp3[0];
#pragma unroll
        for (int f = 0; f < 32; ++f) a += Wp3[f] * h2[f];
        out[b] = a;
    }
}

// ---------------------------------------------------------------------------
extern "C" void kernel_launch(void* const* d_in, const int* in_sizes, int n_in,
                              void* d_out, int out_size, void* d_ws, size_t ws_size,
                              hipStream_t stream) {
    const float* target = (const float*)d_in[0];
    const float* raw    = (const float*)d_in[1];
    const float* W_ih   = (const float*)d_in[2];
    const float* W_hh   = (const float*)d_in[3];
    const float* b_ih   = (const float*)d_in[4];
    const float* b_hh   = (const float*)d_in[5];
    const float* W_Q    = (const float*)d_in[6];
    const float* W_K    = (const float*)d_in[7];
    const float* Wp1    = (const float*)d_in[8];
    const float* bp1    = (const float*)d_in[9];
    const float* Wp2    = (const float*)d_in[10];
    const float* bp2    = (const float*)d_in[11];
    const float* Wp3    = (const float*)d_in[12];
    const float* bp3    = (const float*)d_in[13];

    float* out      = (float*)d_out;
    float* kq       = (float*)d_ws;                 // [512*64] floats
    float* attn_out = out + OFF_ATTN;

    hipLaunchKernelGGL(lstm_kq_kernel, dim3(B_SZ), dim3(256), 0, stream,
                       target, W_ih, W_hh, b_ih, b_hh, W_Q, W_K, kq);
    hipLaunchKernelGGL(attn_stream_kernel, dim3(B_SZ * 4), dim3(256), 0, stream,
                       (const float4*)raw, kq, attn_out);
    hipLaunchKernelGGL(topk_mlp_kernel, dim3(B_SZ), dim3(256), 0, stream,
                       attn_out, raw, Wp1, bp1, Wp2, bp2, Wp3, bp3, out);
}

// Round 5
// 188.621 us; speedup vs baseline: 2.0878x; 1.2864x over previous
//
#include <hip/hip_runtime.h>
#include <math.h>

// Problem constants
#define B_SZ   512
#define L_SEQ  30
#define F_DIM  64
#define N_LEAD 500
#define MAXLAG 10
#define H_DIM  64
#define NROWS  5000          // N_LEAD * MAXLAG
#define TOPK   5

// Output layout (flat float32):
// pred [512] | top_k_indices [512*5*2] | top_k_scores [512*5] | attn [512*5000]
#define OFF_IDX   512
#define OFF_SCORE 5632
#define OFF_ATTN  8192

typedef float v4f __attribute__((ext_vector_type(4)));

__device__ __forceinline__ float fast_sigmoid(float x) {
    return 1.f / (1.f + __expf(-x));
}
__device__ __forceinline__ float fast_tanh(float x) {
    float ax = fabsf(x);
    float t  = __expf(-2.f * ax);
    float r  = (1.f - t) / (1.f + t);
    return copysignf(r, x);
}

// 16 x float4 dot with 4 partial accumulators
__device__ __forceinline__ float dot16(const float4* __restrict__ w,
                                       const float4* __restrict__ v) {
    float a0 = 0.f, a1 = 0.f, a2 = 0.f, a3 = 0.f;
#pragma unroll
    for (int k = 0; k < 16; k += 4) {
        a0 += w[k+0].x*v[k+0].x + w[k+0].y*v[k+0].y + w[k+0].z*v[k+0].z + w[k+0].w*v[k+0].w;
        a1 += w[k+1].x*v[k+1].x + w[k+1].y*v[k+1].y + w[k+1].z*v[k+1].z + w[k+1].w*v[k+1].w;
        a2 += w[k+2].x*v[k+2].x + w[k+2].y*v[k+2].y + w[k+2].z*v[k+2].z + w[k+2].w*v[k+2].w;
        a3 += w[k+3].x*v[k+3].x + w[k+3].y*v[k+3].y + w[k+3].z*v[k+3].z + w[k+3].w*v[k+3].w;
    }
    return (a0 + a1) + (a2 + a3);
}

// ---------------------------------------------------------------------------
// Kernel A: LSTM (30 steps) + query = h@W_Q^T + kq = query@W_K  -> kq[B,64]
// (measured: LSTM + all launch overhead ~ 20.5us)
// ---------------------------------------------------------------------------
__global__ __launch_bounds__(256) void lstm_kq_kernel(
    const float* __restrict__ x,      // [B,30,64]
    const float* __restrict__ W_ih,   // [256,64]
    const float* __restrict__ W_hh,   // [256,64]
    const float* __restrict__ b_ih,   // [256]
    const float* __restrict__ b_hh,   // [256]
    const float* __restrict__ W_Q,    // [64,64]
    const float* __restrict__ W_K,    // [64,64]
    float* __restrict__ kq)           // [B,64]
{
    __shared__ __align__(16) float xs[L_SEQ * F_DIM];   // 7.5 KB
    __shared__ __align__(16) float hs[H_DIM];
    __shared__ __align__(16) float gates[256];

    const int b = blockIdx.x;
    const int t = threadIdx.x;

    for (int i = t; i < L_SEQ * F_DIM; i += 256)
        xs[i] = x[b * L_SEQ * F_DIM + i];
    if (t < H_DIM) hs[t] = 0.f;

    float4 wih[16], whh[16];
    const float4* wihp = (const float4*)(W_ih + t * 64);
    const float4* whhp = (const float4*)(W_hh + t * 64);
#pragma unroll
    for (int k = 0; k < 16; ++k) { wih[k] = wihp[k]; whh[k] = whhp[k]; }
    const float bsum = b_ih[t] + b_hh[t];

    float c = 0.f;
    __syncthreads();

    float gx = bsum + dot16(wih, (const float4*)xs);

    for (int step = 0; step < L_SEQ; ++step) {
        float g = gx + dot16(whh, (const float4*)hs);
        gates[t] = g;
        __syncthreads();
        if (t < H_DIM) {
            float ig = fast_sigmoid(gates[t]);
            float fg = fast_sigmoid(gates[t + 64]);
            float gg = fast_tanh(gates[t + 128]);
            float og = fast_sigmoid(gates[t + 192]);
            c = fg * c + ig * gg;
            hs[t] = og * fast_tanh(c);
        }
        if (step + 1 < L_SEQ)
            gx = bsum + dot16(wih, (const float4*)(xs + (step + 1) * F_DIM));
        __syncthreads();
    }

    if (t < H_DIM)
        gates[t] = dot16((const float4*)(W_Q + t * 64), (const float4*)hs);
    __syncthreads();
    if (t < F_DIM) {
        float a0 = 0.f, a1 = 0.f;
        for (int h = 0; h < H_DIM; h += 2) {
            a0 += gates[h]     * W_K[h * F_DIM + t];
            a1 += gates[h + 1] * W_K[(h + 1) * F_DIM + t];
        }
        kq[b * F_DIM + t] = a0 + a1;
    }
}

// ---------------------------------------------------------------------------
// Kernel B: attn streaming GEMV — R1 wave-contiguous pattern (best measured)
// + NON-TEMPORAL loads on raw (bypass L2/L3 allocation churn).
// 16 lanes coop per row: wave instruction = 1KB contiguous. 5120 blocks.
// ---------------------------------------------------------------------------
#define CHUNKS 10
#define ROWS_PER_BLK 500
__global__ __launch_bounds__(256) void attn_kernel(
    const float* __restrict__ raw,    // [B*5000*64]
    const float* __restrict__ kq,     // [B,64]
    float* __restrict__ attn)         // [B*5000]
{
    const int b     = blockIdx.x / CHUNKS;
    const int chunk = blockIdx.x % CHUNKS;
    const int sub   = threadIdx.x & 15;   // 0..15 : position within row
    const int rg    = threadIdx.x >> 4;   // 0..15 : row group

    const float4 kqv = ((const float4*)(kq + b * 64))[sub];
    const int base   = chunk * ROWS_PER_BLK;
    const size_t rowb = (size_t)b * NROWS;

    for (int it = 0; it < 8; ++it) {
#pragma unroll
        for (int j = 0; j < 4; ++j) {
            int row = base + it * 64 + j * 16 + rg;
            if (row < base + ROWS_PER_BLK) {
                const v4f* pp = (const v4f*)(raw + ((rowb + row) << 6)) + sub;
                v4f v = __builtin_nontemporal_load(pp);
                float s = v.x * kqv.x + v.y * kqv.y + v.z * kqv.z + v.w * kqv.w;
                s += __shfl_xor(s, 8);
                s += __shfl_xor(s, 4);
                s += __shfl_xor(s, 2);
                s += __shfl_xor(s, 1);
                if (sub == 0) attn[rowb + row] = s * 0.125f;
            }
        }
    }
}

// ---------------------------------------------------------------------------
// Kernel C: per-batch top-5 (lax.top_k tie semantics) + softmax + gather + MLP
// ---------------------------------------------------------------------------
__global__ __launch_bounds__(256) void topk_mlp_kernel(
    const float* __restrict__ attn,   // [B*5000]
    const float* __restrict__ raw,    // [B*5000*64]
    const float* __restrict__ Wp1, const float* __restrict__ bp1,
    const float* __restrict__ Wp2, const float* __restrict__ bp2,
    const float* __restrict__ Wp3, const float* __restrict__ bp3,
    float* __restrict__ out)
{
    __shared__ __align__(16) float av[NROWS];       // 20 KB
    __shared__ float redv[4];
    __shared__ int   redi[4];
    __shared__ float topv[TOPK];
    __shared__ int   topi[TOPK];
    __shared__ float sc[TOPK];
    __shared__ __align__(16) float wsum[64];
    __shared__ __align__(16) float h1[64];
    __shared__ float h2[32];

    const int b = blockIdx.x, t = threadIdx.x;

    const float4* ain = (const float4*)(attn + (size_t)b * NROWS);
    float4* av4 = (float4*)av;
    for (int i = t; i < NROWS / 4; i += 256) av4[i] = ain[i];
    __syncthreads();

    for (int pp = 0; pp < TOPK; ++pp) {
        float bv = -INFINITY; int bi = 0x7fffffff;
        for (int i = t; i < NROWS; i += 256) {
            float v = av[i];
            if (v > bv || (v == bv && i < bi)) { bv = v; bi = i; }
        }
#pragma unroll
        for (int m = 32; m >= 1; m >>= 1) {
            float ov = __shfl_xor(bv, m);
            int   oi = __shfl_xor(bi, m);
            if (ov > bv || (ov == bv && oi < bi)) { bv = ov; bi = oi; }
        }
        if ((t & 63) == 0) { redv[t >> 6] = bv; redi[t >> 6] = bi; }
        __syncthreads();
        if (t == 0) {
            for (int w = 1; w < 4; ++w)
                if (redv[w] > bv || (redv[w] == bv && redi[w] < bi)) { bv = redv[w]; bi = redi[w]; }
            topv[pp] = bv; topi[pp] = bi;
            av[bi] = -INFINITY;
        }
        __syncthreads();
    }

    if (t == 0) {
        float mx = topv[0];
        float e[TOPK], s = 0.f;
#pragma unroll
        for (int k = 0; k < TOPK; ++k) { e[k] = __expf(topv[k] - mx); s += e[k]; }
        float inv = 1.f / s;
#pragma unroll
        for (int k = 0; k < TOPK; ++k) {
            sc[k] = e[k] * inv;
            out[OFF_IDX + b * 10 + 2 * k]     = (float)(topi[k] / MAXLAG);
            out[OFF_IDX + b * 10 + 2 * k + 1] = (float)(topi[k] % MAXLAG);
            out[OFF_SCORE + b * TOPK + k]     = sc[k];
        }
    }
    __syncthreads();

    if (t < 64) {
        float acc = 0.f;
#pragma unroll
        for (int k = 0; k < TOPK; ++k)
            acc += sc[k] * raw[((size_t)b * NROWS + topi[k]) * 64 + t];
        wsum[t] = acc;
    }
    __syncthreads();
    if (t < 64) {
        float a = bp1[t];
        const float4* w = (const float4*)(Wp1 + t * 64);
        const float4* v = (const float4*)wsum;
#pragma unroll
        for (int k = 0; k < 16; ++k)
            a += w[k].x*v[k].x + w[k].y*v[k].y + w[k].z*v[k].z + w[k].w*v[k].w;
        h1[t] = fmaxf(a, 0.f);
    }
    __syncthreads();
    if (t < 32) {
        float a = bp2[t];
        const float4* w = (const float4*)(Wp2 + t * 64);
        const float4* v = (const float4*)h1;
#pragma unroll
        for (int k = 0; k < 16; ++k)
            a += w[k].x*v[k].x + w[k].y*v[k].y + w[k].z*v[k].z + w[k].w*v[k].w;
        h2[t] = fmaxf(a, 0.f);
    }
    __syncthreads();
    if (t == 0) {
        float a = bp3[0];
#pragma unroll
        for (int f = 0; f < 32; ++f) a += Wp3[f] * h2[f];
        out[b] = a;
    }
}

// ---------------------------------------------------------------------------
extern "C" void kernel_launch(void* const* d_in, const int* in_sizes, int n_in,
                              void* d_out, int out_size, void* d_ws, size_t ws_size,
                              hipStream_t stream) {
    const float* target = (const float*)d_in[0];
    const float* raw    = (const float*)d_in[1];
    const float* W_ih   = (const float*)d_in[2];
    const float* W_hh   = (const float*)d_in[3];
    const float* b_ih   = (const float*)d_in[4];
    const float* b_hh   = (const float*)d_in[5];
    const float* W_Q    = (const float*)d_in[6];
    const float* W_K    = (const float*)d_in[7];
    const float* Wp1    = (const float*)d_in[8];
    const float* bp1    = (const float*)d_in[9];
    const float* Wp2    = (const float*)d_in[10];
    const float* bp2    = (const float*)d_in[11];
    const float* Wp3    = (const float*)d_in[12];
    const float* bp3    = (const float*)d_in[13];

    float* out      = (float*)d_out;
    float* kq       = (float*)d_ws;                 // [512*64] floats
    float* attn_out = out + OFF_ATTN;

    hipLaunchKernelGGL(lstm_kq_kernel, dim3(B_SZ), dim3(256), 0, stream,
                       target, W_ih, W_hh, b_ih, b_hh, W_Q, W_K, kq);
    hipLaunchKernelGGL(attn_kernel, dim3(B_SZ * CHUNKS), dim3(256), 0, stream,
                       raw, kq, attn_out);
    hipLaunchKernelGGL(topk_mlp_kernel, dim3(B_SZ), dim3(256), 0, stream,
                       attn_out, raw, Wp1, bp1, Wp2, bp2, Wp3, bp3, out);
}